// Round 1
// baseline (2061.498 us; speedup 1.0000x reference)
//
#include <hip/hip_runtime.h>
#include <hip/hip_bf16.h>

constexpr int kH   = 1024;
constexpr int kV   = 128000;
constexpr int kBT  = 2048;     // B*T tokens
constexpr int IGN  = -100;

constexpr int BM = 256;
constexpr int BN = 128;
constexpr int BK = 32;
constexpr int NT = 4;                  // n-tiles (of BN) per block
constexpr int CHUNK  = BN * NT;        // 512 vocab cols per block
constexpr int NCHUNK = kV / CHUNK;     // 250
constexpr int MTILES = kBT / BM;       // 8
constexpr int KSTEPS = kH / BK;        // 32

typedef __attribute__((ext_vector_type(4))) float f32x4;
typedef __attribute__((ext_vector_type(8))) short bf16x8;

static __device__ __forceinline__ unsigned short f2bf(float f) {
  unsigned u = __float_as_uint(f);
  unsigned r = (u + 0x7fffu + ((u >> 16) & 1u)) >> 16;   // RNE
  return (unsigned short)r;
}

// ---------------- x fp32 -> bf16 ----------------
__global__ __launch_bounds__(256)
void convert_x(const float* __restrict__ x, __hip_bfloat16* __restrict__ xb) {
  const int i = (blockIdx.x * 256 + threadIdx.x) * 4;
  const float4 v = *reinterpret_cast<const float4*>(x + i);
  ushort4 p;
  p.x = f2bf(v.x); p.y = f2bf(v.y); p.z = f2bf(v.z); p.w = f2bf(v.w);
  *reinterpret_cast<ushort4*>(xb + i) = p;
}

// ---------------- fused GEMM + per-chunk online-LSE partials ----------------
__global__ __launch_bounds__(512)
void simpo_gemm(const __hip_bfloat16* __restrict__ xb,   // [kBT][kH] bf16
                const float* __restrict__ W,             // [kV][kH] fp32
                float2* __restrict__ partials)           // [kBT][NCHUNK] (max, sumexp)
{
  __shared__ __align__(16) __hip_bfloat16 As[BM * BK];   // 16 KB
  __shared__ __align__(16) __hip_bfloat16 Bs[BN * BK];   // 8 KB
  __shared__ float2 Red[2][BM];                          // 4 KB

  const int tid  = threadIdx.x;
  const int lane = tid & 63;
  const int wid  = tid >> 6;     // 0..7
  const int wr   = wid >> 1;     // 0..3 : row quadrant (64 rows)
  const int wc   = wid & 1;      // 0..1 : col half (64 cols)
  const int l15  = lane & 15;
  const int lhi  = lane >> 4;    // 0..3

  const int chunk = blockIdx.x / MTILES;   // consecutive blocks share the W chunk
  const int mtile = blockIdx.x % MTILES;
  const int mbase = mtile * BM;
  const int nbase0 = chunk * CHUNK;

  // running (max, sumexp) for the 16 rows this lane owns (m=0..3, j=0..3)
  float rmax[16], rsum[16];
#pragma unroll
  for (int i = 0; i < 16; ++i) { rmax[i] = -1e30f; rsum[i] = 0.f; }

  for (int nt = 0; nt < NT; ++nt) {
    const int nbase = nbase0 + nt * BN;
    f32x4 acc[4][4];
#pragma unroll
    for (int m = 0; m < 4; ++m)
#pragma unroll
      for (int n = 0; n < 4; ++n)
        acc[m][n] = (f32x4){0.f, 0.f, 0.f, 0.f};

    for (int kk = 0; kk < KSTEPS; ++kk) {
      const int k0 = kk * BK;
      // stage A: 256x32 bf16, 512 thr x 2 x 16B
#pragma unroll
      for (int i = 0; i < 2; ++i) {
        const int seg = i * 512 + tid;       // 1024 segs of 8 bf16
        const int row = seg >> 2;
        const int kc  = seg & 3;
        const uint4 v = *reinterpret_cast<const uint4*>(
            xb + (size_t)(mbase + row) * kH + k0 + kc * 8);
        *reinterpret_cast<uint4*>(&As[row * BK + kc * 8]) = v;
      }
      // stage B: 128x32 fp32 -> bf16, 512 thr x 2 x float4
#pragma unroll
      for (int i = 0; i < 2; ++i) {
        const int seg = i * 512 + tid;       // 1024 segs of 4 floats
        const int row = seg >> 3;
        const int kc  = seg & 7;
        const float4 v = *reinterpret_cast<const float4*>(
            W + (size_t)(nbase + row) * kH + k0 + kc * 4);
        ushort4 p;
        p.x = f2bf(v.x); p.y = f2bf(v.y); p.z = f2bf(v.z); p.w = f2bf(v.w);
        *reinterpret_cast<ushort4*>(&Bs[row * BK + kc * 4]) = p;
      }
      __syncthreads();

      bf16x8 af[4], bfr[4];
#pragma unroll
      for (int m = 0; m < 4; ++m)
        af[m] = *reinterpret_cast<const bf16x8*>(&As[(wr * 64 + m * 16 + l15) * BK + lhi * 8]);
#pragma unroll
      for (int n = 0; n < 4; ++n)
        bfr[n] = *reinterpret_cast<const bf16x8*>(&Bs[(wc * 64 + n * 16 + l15) * BK + lhi * 8]);
#pragma unroll
      for (int m = 0; m < 4; ++m)
#pragma unroll
        for (int n = 0; n < 4; ++n)
          acc[m][n] = __builtin_amdgcn_mfma_f32_16x16x32_bf16(af[m], bfr[n], acc[m][n], 0, 0, 0);
      __syncthreads();
    }

    // fold this n-tile (64 cols per wave) into running (max,sum); C/D layout:
    // col = l15, row = wr*64 + m*16 + lhi*4 + j
#pragma unroll
    for (int m = 0; m < 4; ++m) {
#pragma unroll
      for (int j = 0; j < 4; ++j) {
        float vmax = fmaxf(fmaxf(acc[m][0][j], acc[m][1][j]),
                           fmaxf(acc[m][2][j], acc[m][3][j]));
#pragma unroll
        for (int s = 1; s < 16; s <<= 1) vmax = fmaxf(vmax, __shfl_xor(vmax, s));
        float ls = __expf(acc[m][0][j] - vmax) + __expf(acc[m][1][j] - vmax)
                 + __expf(acc[m][2][j] - vmax) + __expf(acc[m][3][j] - vmax);
#pragma unroll
        for (int s = 1; s < 16; s <<= 1) ls += __shfl_xor(ls, s);
        const int r = m * 4 + j;
        const float M = fmaxf(rmax[r], vmax);
        rsum[r] = rsum[r] * __expf(rmax[r] - M) + ls * __expf(vmax - M);
        rmax[r] = M;
      }
    }
  }

  // merge the two column-half waves, write one partial per row
  if (l15 == 0) {
#pragma unroll
    for (int m = 0; m < 4; ++m)
#pragma unroll
      for (int j = 0; j < 4; ++j)
        Red[wc][wr * 64 + m * 16 + lhi * 4 + j] =
            make_float2(rmax[m * 4 + j], rsum[m * 4 + j]);
  }
  __syncthreads();
  if (tid < BM) {
    const float2 a = Red[0][tid];
    const float2 b = Red[1][tid];
    const float M = fmaxf(a.x, b.x);
    const float S = a.y * __expf(a.x - M) + b.y * __expf(b.x - M);
    partials[(size_t)(mbase + tid) * NCHUNK + chunk] = make_float2(M, S);
  }
}

// ---------------- target logit: <x[m], W[y[m]]> in fp32, one wave/token ----------------
__global__ __launch_bounds__(256)
void target_dots(const float* __restrict__ x, const int* __restrict__ y,
                 const float* __restrict__ W, float* __restrict__ tgt)
{
  const int wid = threadIdx.x >> 6, lane = threadIdx.x & 63;
  const int m = blockIdx.x * 4 + wid;
  const int label = y[m];
  float s = 0.f;
  if (label >= 0) {
    const float* xr = x + (size_t)m * kH;
    const float* wv = W + (size_t)label * kH;
    for (int i = lane; i < kH; i += 64) s += xr[i] * wv[i];
  }
#pragma unroll
  for (int off = 32; off; off >>= 1) s += __shfl_xor(s, off);
  if (lane == 0) tgt[m] = s;
}

// ---------------- merge 250 partials -> LSE -> masked per-token logp ----------------
__global__ __launch_bounds__(256)
void lse_kernel(const float2* __restrict__ partials, const float* __restrict__ tgt,
                const int* __restrict__ y, float* __restrict__ logp)
{
  const int wid = threadIdx.x >> 6, lane = threadIdx.x & 63;
  const int m = blockIdx.x * 4 + wid;
  const float2* p = partials + (size_t)m * NCHUNK;
  float M = -1e30f, S = 0.f;
  for (int i = lane; i < NCHUNK; i += 64) {
    const float2 v = p[i];
    const float nm = fmaxf(M, v.x);
    S = S * __expf(M - nm) + v.y * __expf(v.x - nm);
    M = nm;
  }
#pragma unroll
  for (int off = 32; off; off >>= 1) {
    const float oM = __shfl_xor(M, off), oS = __shfl_xor(S, off);
    const float nm = fmaxf(M, oM);
    S = S * __expf(M - nm) + oS * __expf(oM - nm);
    M = nm;
  }
  if (lane == 0) {
    const float lse = logf(S) + M;
    logp[m] = (y[m] != IGN) ? (tgt[m] - lse) : 0.f;
  }
}

// ---------------- per-sequence average + SimPO loss ----------------
__global__ __launch_bounds__(256)
void final_kernel(const float* __restrict__ logp, const int* __restrict__ y,
                  float* __restrict__ out)
{
  __shared__ float ssum[4][256];
  __shared__ int   scnt[4][256];
  __shared__ float avg[4];
  const int tid = threadIdx.x;
  float s0 = 0.f, s1 = 0.f, s2 = 0.f, s3 = 0.f;
  int   c0 = 0,  c1 = 0,  c2 = 0,  c3 = 0;
  { int m;
    m = tid;        if (y[m] != IGN) { s0 += logp[m]; c0++; }
    m = tid + 256;  if (y[m] != IGN) { s0 += logp[m]; c0++; }
    m = tid + 512;  if (y[m] != IGN) { s1 += logp[m]; c1++; }
    m = tid + 768;  if (y[m] != IGN) { s1 += logp[m]; c1++; }
    m = tid + 1024; if (y[m] != IGN) { s2 += logp[m]; c2++; }
    m = tid + 1280; if (y[m] != IGN) { s2 += logp[m]; c2++; }
    m = tid + 1536; if (y[m] != IGN) { s3 += logp[m]; c3++; }
    m = tid + 1792; if (y[m] != IGN) { s3 += logp[m]; c3++; }
  }
  ssum[0][tid] = s0; ssum[1][tid] = s1; ssum[2][tid] = s2; ssum[3][tid] = s3;
  scnt[0][tid] = c0; scnt[1][tid] = c1; scnt[2][tid] = c2; scnt[3][tid] = c3;
  __syncthreads();
  if (tid < 4) {
    float s = 0.f; int c = 0;
    for (int i = 0; i < 256; ++i) { s += ssum[tid][i]; c += scnt[tid][i]; }
    avg[tid] = s / (float)(c > 0 ? c : 1);
  }
  __syncthreads();
  if (tid == 0) {
    const float BETA = 0.1f, GAMMA = 0.5f;
    const float d0 = BETA * (avg[0] - avg[2]) - GAMMA;
    const float d1 = BETA * (avg[1] - avg[3]) - GAMMA;
    const float z0 = -d0, z1 = -d1;
    const float l0 = fmaxf(z0, 0.f) + log1pf(expf(-fabsf(z0)));
    const float l1 = fmaxf(z1, 0.f) + log1pf(expf(-fabsf(z1)));
    out[0] = 0.5f * (l0 + l1);
  }
}

extern "C" void kernel_launch(void* const* d_in, const int* in_sizes, int n_in,
                              void* d_out, int out_size, void* d_ws, size_t ws_size,
                              hipStream_t stream)
{
  const float* x = (const float*)d_in[0];
  const int*   y = (const int*)d_in[1];
  const float* W = (const float*)d_in[2];
  float* out = (float*)d_out;

  char* ws = (char*)d_ws;
  float2* partials        = (float2*)ws;                               // 4,096,000 B
  __hip_bfloat16* xb      = (__hip_bfloat16*)(ws + 4096000);           // 4,194,304 B
  float* tgt              = (float*)(ws + 4096000 + 4194304);          // 8 KB
  float* logp             = (float*)(ws + 4096000 + 4194304 + 8192);   // 8 KB

  convert_x  <<<kBT * kH / 1024, 256, 0, stream>>>(x, xb);
  simpo_gemm <<<NCHUNK * MTILES, 512, 0, stream>>>(xb, W, partials);
  target_dots<<<kBT / 4, 256, 0, stream>>>(x, y, W, tgt);
  lse_kernel <<<kBT / 4, 256, 0, stream>>>(partials, tgt, y, logp);
  final_kernel<<<1, 256, 0, stream>>>(logp, y, out);
}